// Round 15
// baseline (381.614 us; speedup 1.0000x reference)
//
#include <hip/hip_runtime.h>
#include <hip/hip_bf16.h>
#include <stdint.h>

#define B_ 256
#define H_ 4096
#define K_ 32768   // V*N = 1024*32

typedef __attribute__((ext_vector_type(8))) short bf16x8;
typedef __attribute__((ext_vector_type(4))) float f32x4;

__device__ __forceinline__ unsigned short f2bf(float x) {
    union { float f; unsigned int u; } c; c.f = x;
    unsigned int r = c.u + 0x7FFFu + ((c.u >> 16) & 1u);  // RNE
    return (unsigned short)(r >> 16);
}

__device__ __forceinline__ short bfc(float x) {
    __hip_bfloat16 h = __float2bfloat16(x);
    union { __hip_bfloat16 h; short s; } c; c.h = h;
    return c.s;
}

__device__ __forceinline__ float softplus_f(float x) {
    return fmaxf(x, 0.0f) + log1pf(expf(-fabsf(x)));
}

// ---------------- Kernel A: v fp32->bf16 + vt[b] = dot(v[b,:], b_v) ----------------
__global__ __launch_bounds__(256) void prep_kernel(
    const float* __restrict__ v, const float* __restrict__ bv,
    __hip_bfloat16* __restrict__ vbf, float* __restrict__ vt)
{
    const int b = blockIdx.x;
    const int t = threadIdx.x;
    const float* vr = v + (size_t)b * K_;
    unsigned short* dr = (unsigned short*)(vbf + (size_t)b * K_);
    float acc = 0.f;
    for (int i = t * 8; i < K_; i += 256 * 8) {
        float4 x0 = *(const float4*)(vr + i);
        float4 x1 = *(const float4*)(vr + i + 4);
        float4 b0 = *(const float4*)(bv + i);
        float4 b1 = *(const float4*)(bv + i + 4);
        acc += x0.x*b0.x + x0.y*b0.y + x0.z*b0.z + x0.w*b0.w
             + x1.x*b1.x + x1.y*b1.y + x1.z*b1.z + x1.w*b1.w;
        ushort4 u0, u1;
        u0.x = f2bf(x0.x); u0.y = f2bf(x0.y); u0.z = f2bf(x0.z); u0.w = f2bf(x0.w);
        u1.x = f2bf(x1.x); u1.y = f2bf(x1.y); u1.z = f2bf(x1.z); u1.w = f2bf(x1.w);
        *(ushort4*)(dr + i)     = u0;
        *(ushort4*)(dr + i + 4) = u1;
    }
    __shared__ float sm[256];
    sm[t] = acc;
    __syncthreads();
    for (int s = 128; s > 0; s >>= 1) {
        if (t < s) sm[t] += sm[t + s];
        __syncthreads();
    }
    if (t == 0) vt[b] = sm[0];
}

// ---------------- Kernel B: producer-consumer GEMM, BM=256 BN=128 BK=256 ----------------
// SINGLE-VARIABLE CHANGE vs R14: producer reads W as one-row-per-instruction
// 1 KB bursts (lane l -> bytes l*16.. of ONE row), walking rows sequentially —
// instead of one instruction spanning 8-16 rows at 128 KB stride. Tests whether
// per-instruction burst contiguity is what capped W delivery at ~3 TB/s.
// Skeleton identical to R14 (passed): depth-2 ring of [128][256] bf16 tiles,
// 8 consumers (32M x 128N; per body 8 phases x {2 A-loads, 8 ds_read_b128,
// 16 MFMA}) + 2 producers; 1 barrier/body; NT=8 bodies (KS=16).
//
// Producer pipeline: 8 statically-named float4 bufs (rule #20); 1 load/piece;
// steady vmcnt(7) drains exactly the piece about to be written; final tile's
// last 8 pieces drain descending 7..0. Issue-ahead crosses tile boundaries
// (loads only — safe across barriers).
// Ring: producer writes tile T -> slot T&1 between barriers T-1 and T;
// consumer body t reads slot t&1 between barriers t and t+1. Disjoint.
// Barriers: both roles NT+1.
//
// LDS swizzle: granule g' = g ^ (row&15) (32 granules/row of 16 B).
//  - write: one row per instruction -> banks swept sequentially (optimal).
//  - read (consumer): 16 rows x g^lr -> 16 distinct granules, 2-way (free).

#define NCONS 8
#define VMW(N)  asm volatile("s_waitcnt vmcnt(" #N ")" ::: "memory")
#define PBAR()  asm volatile("s_waitcnt lgkmcnt(0)\n\ts_barrier" ::: "memory")
#define CBAR()  asm volatile("s_barrier" ::: "memory")

// load piece (tile TT, row-idx II within this wave's 64 rows): 1 KB of one row
#define PLD(BUF, TT, II) \
    BUF = *(const float4*)(wsrc0 + (size_t)(II) * K_ + (size_t)(TT) * 256)

// cvt + swizzled write of piece II into ring slot SLOT_ (ushort base)
#define PST(BUF, SLOT_, II) do {                                                       \
    short4 u_;                                                                         \
    u_.x = bfc(BUF.x); u_.y = bfc(BUF.y); u_.z = bfc(BUF.z); u_.w = bfc(BUF.w);        \
    *(short4*)&wtile[(SLOT_) + (r0 + (II)) * 256 +                                     \
                     (((lane >> 1) ^ ((II) & 15)) * 8) + ((lane & 1) * 4)] = u_;       \
    } while (0)

#define STEP(BUF, II, NTT, NII) do {                                                   \
    VMW(7);                                                                            \
    PST(BUF, slot, II);                                                                \
    PLD(BUF, NTT, NII);                                                                \
    } while (0)

__global__ __launch_bounds__(640, 4) void gemm_kernel(
    const __hip_bfloat16* __restrict__ vbf,   // [256][32768] bf16
    const float* __restrict__ W,              // [4096][32768] fp32
    float* __restrict__ part,                 // [KS][256][4096] fp32
    int KS, int NT)                           // NT = (K_/KS)/256, >= 2
{
    __shared__ __align__(16) unsigned short wtile[2 * 128 * 256];  // 128 KB ring

    const int tid  = threadIdx.x;
    const int wid  = tid >> 6;
    const int lane = tid & 63;
    const int lr   = lane & 15;
    const int lg   = lane >> 4;

    const int bid   = blockIdx.x;
    const int sidx  = bid % KS;
    const int ht    = bid / KS;
    const int h0    = ht * 128;
    const int kbase = sidx * (NT * 256);

    if (wid < NCONS) {
        // ---------------- consumer: 32 M-rows x 128 N-cols ----------------
        const __hip_bfloat16* ap0 = vbf + (size_t)(wid * 32 + lr) * K_ + kbase + lg * 8;
        const __hip_bfloat16* ap1 = ap0 + (size_t)16 * K_;

        f32x4 acc[2][8];
        #pragma unroll
        for (int m = 0; m < 2; ++m)
            #pragma unroll
            for (int n = 0; n < 8; ++n)
                acc[m][n] = (f32x4)(0.0f);

        CBAR();   // barrier 0: tile 0 staged

        for (int t = 0; t < NT; ++t) {
            const unsigned short* wb = &wtile[(t & 1) * 32768];
            const size_t koff = (size_t)t * 256;
            #pragma unroll
            for (int s = 0; s < 8; ++s) {
                bf16x8 a0 = *(const bf16x8*)(ap0 + koff + s * 32);
                bf16x8 a1 = *(const bf16x8*)(ap1 + koff + s * 32);
                #pragma unroll
                for (int q = 0; q < 2; ++q) {
                    bf16x8 bfr[4];
                    #pragma unroll
                    for (int n = 0; n < 4; ++n) {
                        int row = (q * 4 + n) * 16 + lr;
                        int g   = (s * 4 + lg) ^ lr;      // row & 15 == lr
                        bfr[n] = *(const bf16x8*)&wb[row * 256 + g * 8];
                    }
                    #pragma unroll
                    for (int n = 0; n < 4; ++n) {
                        acc[0][q*4+n] = __builtin_amdgcn_mfma_f32_16x16x32_bf16(
                            a0, bfr[n], acc[0][q*4+n], 0, 0, 0);
                        acc[1][q*4+n] = __builtin_amdgcn_mfma_f32_16x16x32_bf16(
                            a1, bfr[n], acc[1][q*4+n], 0, 0, 0);
                    }
                }
            }
            CBAR();
        }

        // Epilogue: C/D layout col=lane&15 (=h), row=(lane>>4)*4+reg (=b)
        float* pout = part + (size_t)sidx * ((size_t)B_ * H_) + h0;
        #pragma unroll
        for (int m = 0; m < 2; ++m)
            #pragma unroll
            for (int n = 0; n < 8; ++n)
                #pragma unroll
                for (int j = 0; j < 4; ++j) {
                    int brow = wid * 32 + m * 16 + lg * 4 + j;
                    int hcol = n * 16 + lr;
                    pout[(size_t)brow * H_ + hcol] = acc[m][n][j];
                }
    } else {
        // ---------------- producer: linear 1-KB single-row bursts ----------------
        const int pw = wid - NCONS;            // 0..1
        const int r0 = pw * 64;                // this wave's row base (0 or 64)
        const float* wsrc0 = W + (size_t)(h0 + r0) * K_ + kbase + lane * 4;

        float4 b0, b1, b2, b3, b4, b5, b6, b7;

        // warm pipeline: pieces 0..7 of tile 0
        PLD(b0, 0, 0); PLD(b1, 0, 1); PLD(b2, 0, 2); PLD(b3, 0, 3);
        PLD(b4, 0, 4); PLD(b5, 0, 5); PLD(b6, 0, 6); PLD(b7, 0, 7);

        for (int T = 0; T < NT; ++T) {
            const int slot = (T & 1) * 32768;
            #pragma unroll
            for (int i0 = 0; i0 < 56; i0 += 8) {
                STEP(b0, i0 + 0, T, i0 +  8); STEP(b1, i0 + 1, T, i0 +  9);
                STEP(b2, i0 + 2, T, i0 + 10); STEP(b3, i0 + 3, T, i0 + 11);
                STEP(b4, i0 + 4, T, i0 + 12); STEP(b5, i0 + 5, T, i0 + 13);
                STEP(b6, i0 + 6, T, i0 + 14); STEP(b7, i0 + 7, T, i0 + 15);
            }
            if (T + 1 < NT) {   // last group: issue pieces 0..7 of tile T+1
                STEP(b0, 56, T + 1, 0); STEP(b1, 57, T + 1, 1);
                STEP(b2, 58, T + 1, 2); STEP(b3, 59, T + 1, 3);
                STEP(b4, 60, T + 1, 4); STEP(b5, 61, T + 1, 5);
                STEP(b6, 62, T + 1, 6); STEP(b7, 63, T + 1, 7);
            } else {            // final tile: descending drain, no issues
                VMW(7); PST(b0, slot, 56);
                VMW(6); PST(b1, slot, 57);
                VMW(5); PST(b2, slot, 58);
                VMW(4); PST(b3, slot, 59);
                VMW(3); PST(b4, slot, 60);
                VMW(2); PST(b5, slot, 61);
                VMW(1); PST(b6, slot, 62);
                VMW(0); PST(b7, slot, 63);
            }
            PBAR();
        }
        PBAR();   // matches consumers' final body barrier
    }
}

// ---------------- Kernel C: reduce splits + b_h, softplus, sum over H, + vt ----------------
__global__ __launch_bounds__(256) void reduce_kernel(
    const float* __restrict__ part, const float* __restrict__ bh,
    const float* __restrict__ vt, float* __restrict__ out, int KS)
{
    const int b = blockIdx.x;
    const int t = threadIdx.x;
    float sp = 0.f;
    const float* pb = part + (size_t)b * H_;
    for (int h = t * 4; h < H_; h += 256 * 4) {
        float4 l = *(const float4*)(bh + h);
        for (int s = 0; s < KS; ++s) {
            float4 p = *(const float4*)(pb + (size_t)s * B_ * H_ + h);
            l.x += p.x; l.y += p.y; l.z += p.z; l.w += p.w;
        }
        sp += softplus_f(l.x) + softplus_f(l.y) + softplus_f(l.z) + softplus_f(l.w);
    }
    __shared__ float sm[256];
    sm[t] = sp;
    __syncthreads();
    for (int r = 128; r > 0; r >>= 1) {
        if (t < r) sm[t] += sm[t + r];
        __syncthreads();
    }
    if (t == 0) out[b] = sm[0] + vt[b];
}

extern "C" void kernel_launch(void* const* d_in, const int* in_sizes, int n_in,
                              void* d_out, int out_size, void* d_ws, size_t ws_size,
                              hipStream_t stream)
{
    const float* v  = (const float*)d_in[0];
    const float* W  = (const float*)d_in[1];
    const float* bh = (const float*)d_in[2];
    const float* bv = (const float*)d_in[3];
    float* out = (float*)d_out;

    char* ws = (char*)d_ws;
    const size_t vbf_bytes = (size_t)B_ * K_ * sizeof(__hip_bfloat16);  // 16 MB
    __hip_bfloat16* vbf = (__hip_bfloat16*)ws;

    int KS = 16;                                  // shrink if workspace is small
    while (KS > 1 && vbf_bytes + (size_t)KS * B_ * H_ * 4 + 1024 > ws_size) KS >>= 1;

    float* part = (float*)(ws + vbf_bytes);                                  // KS*4 MB
    float* vt   = (float*)(ws + vbf_bytes + (size_t)KS * B_ * H_ * 4);       // 1 KB

    prep_kernel<<<B_, 256, 0, stream>>>(v, bv, vbf, vt);
    const int NT = (K_ / KS) / 256;               // 8 for KS=16
    gemm_kernel<<<(H_ / 128) * KS, 640, 0, stream>>>(vbf, W, part, KS, NT);
    reduce_kernel<<<B_, 256, 0, stream>>>(part, bh, vt, out, KS);
}

// Round 16
// 182.668 us; speedup vs baseline: 2.0891x; 2.0891x over previous
//
#include <hip/hip_runtime.h>
#include <hip/hip_bf16.h>
#include <stdint.h>

#define B_ 256
#define H_ 4096
#define K_ 32768   // V*N = 1024*32

typedef __attribute__((ext_vector_type(8))) short bf16x8;
typedef __attribute__((ext_vector_type(4))) float f32x4;

__device__ __forceinline__ unsigned short f2bf(float x) {
    union { float f; unsigned int u; } c; c.f = x;
    unsigned int r = c.u + 0x7FFFu + ((c.u >> 16) & 1u);  // RNE
    return (unsigned short)(r >> 16);
}

__device__ __forceinline__ short bfc(float x) {
    __hip_bfloat16 h = __float2bfloat16(x);
    union { __hip_bfloat16 h; short s; } c; c.h = h;
    return c.s;
}

__device__ __forceinline__ float softplus_f(float x) {
    return fmaxf(x, 0.0f) + log1pf(expf(-fabsf(x)));
}

// ---------------- Kernel A: v fp32->bf16 + vt[b] = dot(v[b,:], b_v) ----------------
__global__ __launch_bounds__(256) void prep_kernel(
    const float* __restrict__ v, const float* __restrict__ bv,
    __hip_bfloat16* __restrict__ vbf, float* __restrict__ vt)
{
    const int b = blockIdx.x;
    const int t = threadIdx.x;
    const float* vr = v + (size_t)b * K_;
    unsigned short* dr = (unsigned short*)(vbf + (size_t)b * K_);
    float acc = 0.f;
    for (int i = t * 8; i < K_; i += 256 * 8) {
        float4 x0 = *(const float4*)(vr + i);
        float4 x1 = *(const float4*)(vr + i + 4);
        float4 b0 = *(const float4*)(bv + i);
        float4 b1 = *(const float4*)(bv + i + 4);
        acc += x0.x*b0.x + x0.y*b0.y + x0.z*b0.z + x0.w*b0.w
             + x1.x*b1.x + x1.y*b1.y + x1.z*b1.z + x1.w*b1.w;
        ushort4 u0, u1;
        u0.x = f2bf(x0.x); u0.y = f2bf(x0.y); u0.z = f2bf(x0.z); u0.w = f2bf(x0.w);
        u1.x = f2bf(x1.x); u1.y = f2bf(x1.y); u1.z = f2bf(x1.z); u1.w = f2bf(x1.w);
        *(ushort4*)(dr + i)     = u0;
        *(ushort4*)(dr + i + 4) = u1;
    }
    __shared__ float sm[256];
    sm[t] = acc;
    __syncthreads();
    for (int s = 128; s > 0; s >>= 1) {
        if (t < s) sm[t] += sm[t + s];
        __syncthreads();
    }
    if (t == 0) vt[b] = sm[0];
}

// ---------------- Kernel B: producer-consumer split-K GEMM, BM=256 BN=128 BK=64 ----------------
// R12 champion + ONE change: per-block k-phase rotation. Body t processes
// physical k-tile KP(t) = (t + phase) & (NT-1); phase = hash(bid). Breaks the
// device-wide lockstep where all blocks read the same 256-B column window of
// their 128KB-strided W rows at the same instant (DRAM channel/bank collision
// suspected to cap W delivery at ~3 TB/s in R3/R9/R12/R14).
// Everything else identical to R12 (passed, 197.8 us): KS=16, 640 threads,
// 8 consumers (32M x 128N, acc[2][8]; A single-buffered in two s-halves),
// 2 producers (W fp32 -> regs 2-deep -> cvt bf16 -> swizzled ds_write into
// depth-4 16KB ring), 1 barrier/body, NT+1 barriers both roles.

#define NCONS 8

#define LOAD_AS(S_, kt) do {                                                           \
    aC[(S_)]     = *(const bf16x8*)(ap[0] + (size_t)KP(kt) * 64 + (S_) * 32);          \
    aC[2 + (S_)] = *(const bf16x8*)(ap[1] + (size_t)KP(kt) * 64 + (S_) * 32);          \
    } while (0)

#define COMPUTE_S(T_, S_) do {                                                         \
    const unsigned short* wb_ = &wtile[(T_) & 3][0];                                   \
    _Pragma("unroll")                                                                  \
    for (int q_ = 0; q_ < 2; ++q_) {                                                   \
        bf16x8 bfr[4];                                                                 \
        _Pragma("unroll")                                                              \
        for (int n_ = 0; n_ < 4; ++n_) {                                               \
            int row_ = (q_ * 4 + n_) * 16 + lr;                                        \
            bfr[n_] = *(const bf16x8*)&wb_[row_ * 64 +                                 \
                        ((((S_) * 4 + lg) ^ (row_ & 7)) << 3)];                        \
        }                                                                              \
        _Pragma("unroll")                                                              \
        for (int m_ = 0; m_ < 2; ++m_)                                                 \
            _Pragma("unroll")                                                          \
            for (int n_ = 0; n_ < 4; ++n_)                                             \
                acc[m_][q_ * 4 + n_] = __builtin_amdgcn_mfma_f32_16x16x32_bf16(        \
                    aC[m_ * 2 + (S_)], bfr[n_], acc[m_][q_ * 4 + n_], 0, 0, 0);        \
    } } while (0)

#define PISS(dst, TT, HH) do {                                                         \
    _Pragma("unroll")                                                                  \
    for (int j_ = 0; j_ < 4; ++j_) {                                                   \
        const float* p_ = prow[j_] + (size_t)(HH) * 64 * K_                            \
                                   + (size_t)KP(TT) * 64;                              \
        dst[2*j_]   = *(const float4*)p_;                                              \
        dst[2*j_+1] = *(const float4*)(p_ + 4);                                        \
    } } while (0)

#define PWRITE(src, T_, HALF_) do {                                                    \
    _Pragma("unroll")                                                                  \
    for (int j_ = 0; j_ < 4; ++j_) {                                                   \
        int R_ = (HALF_) * 64 + j_ * 16 + pw * 8 + r8;                                 \
        float4 a_ = src[2*j_], b_ = src[2*j_+1];                                       \
        bf16x8 u_;                                                                     \
        u_[0]=bfc(a_.x); u_[1]=bfc(a_.y); u_[2]=bfc(a_.z); u_[3]=bfc(a_.w);            \
        u_[4]=bfc(b_.x); u_[5]=bfc(b_.y); u_[6]=bfc(b_.z); u_[7]=bfc(b_.w);            \
        *(bf16x8*)&wtile[(T_) & 3][R_ * 64 + swz] = u_;                                \
    } } while (0)

#define VMW(N)  asm volatile("s_waitcnt vmcnt(" #N ")" ::: "memory")
#define PBAR()  asm volatile("s_waitcnt lgkmcnt(0)\n\ts_barrier" ::: "memory")
#define CBAR()  asm volatile("s_barrier" ::: "memory")

__global__ __launch_bounds__(640, 4) void gemm_kernel(
    const __hip_bfloat16* __restrict__ vbf,   // [256][32768] bf16
    const float* __restrict__ W,              // [4096][32768] fp32
    float* __restrict__ part,                 // [KS][256][4096] fp32
    int KS, int NT)                           // NT = (K_/KS)/64, power of 2, >= 4
{
    __shared__ __align__(16) unsigned short wtile[4][128 * 64];  // 4 x 16 KB bf16 ring

    const int tid  = threadIdx.x;
    const int wid  = tid >> 6;
    const int lane = tid & 63;
    const int lr   = lane & 15;
    const int lg   = lane >> 4;

    const int bid   = blockIdx.x;
    const int sidx  = bid % KS;
    const int ht    = bid / KS;
    const int h0    = ht * 128;
    const int kbase = sidx * (NT * 64);

    // Per-block k-phase rotation (the single change vs R12):
    const int ntm   = NT - 1;
    const int phase = (int)(((unsigned)bid * 2654435761u) >> 27) & ntm;
#define KP(T) (((T) + phase) & ntm)

    if (wid < NCONS) {
        // ---------------- consumer: 32 M-rows x 128 N-cols ----------------
        const __hip_bfloat16* ap[2];
        #pragma unroll
        for (int m = 0; m < 2; ++m)
            ap[m] = vbf + (size_t)(wid * 32 + m * 16 + lr) * K_ + kbase + lg * 8;

        f32x4 acc[2][8];
        #pragma unroll
        for (int m = 0; m < 2; ++m)
            #pragma unroll
            for (int n = 0; n < 8; ++n)
                acc[m][n] = (f32x4)(0.0f);

        bf16x8 aC[4];              // [m*2+s]
        LOAD_AS(0, 0);
        LOAD_AS(1, 0);
        CBAR();                    // prologue: slot 0 ready

        for (int t = 0; t < NT; ++t) {
            const bool last = (t == NT - 1);
            COMPUTE_S(t, 0);       // compiler waits exactly on aC[0],aC[2]
            if (!last) LOAD_AS(0, t + 1);   // WAR: ordered after s0 MFMAs
            COMPUTE_S(t, 1);
            if (!last) LOAD_AS(1, t + 1);
            CBAR();
        }

        // Epilogue: C/D layout col=lane&15 (=h), row=(lane>>4)*4+reg (=b)
        float* pout = part + (size_t)sidx * ((size_t)B_ * H_) + h0;
        #pragma unroll
        for (int m = 0; m < 2; ++m)
            #pragma unroll
            for (int n = 0; n < 8; ++n)
                #pragma unroll
                for (int j = 0; j < 4; ++j) {
                    int brow = wid * 32 + m * 16 + lg * 4 + j;
                    int hcol = n * 16 + lr;
                    pout[(size_t)brow * H_ + hcol] = acc[m][n][j];
                }
    } else {
        // ---------------- producer: stage [128][64] fp32 -> bf16 ring ----------------
        const int pw = wid - NCONS;   // 0..1
        const int l8 = lane & 7;      // 8-float granule within row
        const int r8 = lane >> 3;     // row-sub 0..7
        const float* prow[4];
        #pragma unroll
        for (int j = 0; j < 4; ++j)
            prow[j] = W + (size_t)(h0 + j * 16 + pw * 8 + r8) * K_ + kbase + l8 * 8;
        const int swz = ((l8 ^ r8) << 3);   // ushort offset; R&7 == r8

        float4 bufA[8], bufB[8];

        // prologue: body 0 (tile 0, halves 0,1) -> slot 0; tile 1 in flight
        PISS(bufA, 0, 0);
        PISS(bufB, 0, 1);
        VMW(8);  PWRITE(bufA, 0, 0);  PISS(bufA, 1, 0);
        VMW(8);  PWRITE(bufB, 0, 1);  PISS(bufB, 1, 1);
        PBAR();

        for (int t = 0; t < NT - 1; ++t) {
            const bool lastp = (t == NT - 2);
            VMW(8);
            PWRITE(bufA, t + 1, 0);
            if (!lastp) PISS(bufA, t + 2, 0);
            if (lastp) { VMW(0); } else { VMW(8); }
            PWRITE(bufB, t + 1, 1);
            if (!lastp) PISS(bufB, t + 2, 1);
            PBAR();
        }
        PBAR();   // matches consumers' final body barrier
    }
#undef KP
}

// ---------------- Kernel C: reduce splits + b_h, softplus, sum over H, + vt ----------------
__global__ __launch_bounds__(256) void reduce_kernel(
    const float* __restrict__ part, const float* __restrict__ bh,
    const float* __restrict__ vt, float* __restrict__ out, int KS)
{
    const int b = blockIdx.x;
    const int t = threadIdx.x;
    float sp = 0.f;
    const float* pb = part + (size_t)b * H_;
    for (int h = t * 4; h < H_; h += 256 * 4) {
        float4 l = *(const float4*)(bh + h);
        for (int s = 0; s < KS; ++s) {
            float4 p = *(const float4*)(pb + (size_t)s * B_ * H_ + h);
            l.x += p.x; l.y += p.y; l.z += p.z; l.w += p.w;
        }
        sp += softplus_f(l.x) + softplus_f(l.y) + softplus_f(l.z) + softplus_f(l.w);
    }
    __shared__ float sm[256];
    sm[t] = sp;
    __syncthreads();
    for (int r = 128; r > 0; r >>= 1) {
        if (t < r) sm[t] += sm[t + r];
        __syncthreads();
    }
    if (t == 0) out[b] = sm[0] + vt[b];
}

extern "C" void kernel_launch(void* const* d_in, const int* in_sizes, int n_in,
                              void* d_out, int out_size, void* d_ws, size_t ws_size,
                              hipStream_t stream)
{
    const float* v  = (const float*)d_in[0];
    const float* W  = (const float*)d_in[1];
    const float* bh = (const float*)d_in[2];
    const float* bv = (const float*)d_in[3];
    float* out = (float*)d_out;

    char* ws = (char*)d_ws;
    const size_t vbf_bytes = (size_t)B_ * K_ * sizeof(__hip_bfloat16);  // 16 MB
    __hip_bfloat16* vbf = (__hip_bfloat16*)ws;

    int KS = 16;                                  // shrink if workspace is small
    while (KS > 1 && vbf_bytes + (size_t)KS * B_ * H_ * 4 + 1024 > ws_size) KS >>= 1;

    float* part = (float*)(ws + vbf_bytes);                                  // KS*4 MB
    float* vt   = (float*)(ws + vbf_bytes + (size_t)KS * B_ * H_ * 4);       // 1 KB

    prep_kernel<<<B_, 256, 0, stream>>>(v, bv, vbf, vt);
    const int NT = (K_ / KS) / 64;                // 32 for KS=16 (power of 2)
    gemm_kernel<<<(H_ / 128) * KS, 640, 0, stream>>>(vbf, W, part, KS, NT);
    reduce_kernel<<<B_, 256, 0, stream>>>(part, bh, vt, out, KS);
}